// Round 8
// baseline (243.948 us; speedup 1.0000x reference)
//
#include <hip/hip_runtime.h>

// Problem constants
constexpr int   kAtoms  = 5000;
constexpr int   kPairs  = 160000;
constexpr int   KD      = 128;   // K
constexpr int   NB      = 8;     // N_BASIS
constexpr int   RH      = 32;    // RAD_HIDDEN
constexpr float kCutoff = 5.0f;
constexpr float kPi     = 3.14159265358979323846f;
constexpr float C1 = 0.2f * 0.1767767f;   // INIT_SCALE * MSG_SCALE
constexpr float C2 = 1.2f * 0.1767767f;   // (1+INIT_SCALE) * MSG_SCALE

__device__ __forceinline__ float silu(float x) { return x / (1.0f + __expf(-x)); }

// Only the l=0 channel reaches the output; l>=1 / sph / U2 are dead code.
//   F0[a][k] = C1*( b2[k]*sum_s n_s*e_s[k] + sum_s e_s[k]*sum_j w2[j][k]*H_s[j] )
//   G0 = F0+F0^2*mix
//   D[a][k]  = sum_p Re0_p[k]*G0[nbr_p][k];   n = G0+C2*D;  V = n+n^2*emix
//   out = head MLP(V)
// R8 REDESIGN: CSR (hist/scan/build-reorder) eliminated. H and D are built
// by PAIR-PARALLEL kernels with fp32 atomicAdd (order-independent sums;
// test threshold 1.3e-3 >> atomic reorder noise ~1e-6). Perfect load
// balance, no imbalanced barriers, 5 dispatches instead of 7.
// GFX950 NOTES (rounds 1-7):
//   - __launch_bounds__(B, w) caps VGPRs at 256/w; w>=6 -> 40-reg cap ->
//     scratch spill (WRITE_SIZE 13-123MB). Keep cap >> working set.
//   - Single-wave WGs cap ~8 WGs/CU; but 4-wave atom-packed d0 (R7) was
//     WORSE (58 vs 50us): nch_max barrier coupling + imbalance ate it.
//   - Multi-wave blocks: read block-shared LDS only AFTER the publishing
//     __syncthreads (R5 race).
//   - Never single-block pipeline stages (R6 prep: 1-CU bandwidth, 60us).

// ---------------------------------------------------------------------------
// K1: pair-parallel. Per pair: geometry -> rbf (stored coalesced), h_rad
// via j-across-lanes, atomicAdd into H[ci][spec][j] and ncnt[ci][spec].
// ---------------------------------------------------------------------------
__global__ __launch_bounds__(256) void build2_kernel(
    const float* __restrict__ pos, const float* __restrict__ cells,
    const int* __restrict__ species, const int* __restrict__ shifts,
    const int* __restrict__ ctr, const int* __restrict__ nbr,
    const int* __restrict__ spair,
    const float* __restrict__ w1, const float* __restrict__ b1,
    float* __restrict__ rbf_s, float* __restrict__ H, int* __restrict__ ncnt)
{
    __shared__ float s_w1[NB][RH];
    __shared__ float s_b1v[RH];
    __shared__ float s_rbf[256][NB];   // 8 KB
    __shared__ int   s_ci[256];
    __shared__ int   s_sp[256];

    int t = threadIdx.x;
    for (int idx = t; idx < NB * RH; idx += 256)
        s_w1[idx >> 5][idx & 31] = w1[idx];
    if (t < RH) s_b1v[t] = b1[t];

    int p  = blockIdx.x * 256 + t;
    int ci = ctr[p], ni = nbr[p], sp = spair[p];
    float s0 = (float)shifts[p * 3 + 0] - 1.0f;
    float s1 = (float)shifts[p * 3 + 1] - 1.0f;
    float s2 = (float)shifts[p * 3 + 2] - 1.0f;
    const float* C = cells + sp * 9;
    float vx = pos[ni * 3 + 0] - pos[ci * 3 + 0] + s0 * C[0] + s1 * C[3] + s2 * C[6];
    float vy = pos[ni * 3 + 1] - pos[ci * 3 + 1] + s0 * C[1] + s1 * C[4] + s2 * C[7];
    float vz = pos[ni * 3 + 2] - pos[ci * 3 + 2] + s0 * C[2] + s1 * C[5] + s2 * C[8];
    float d = sqrtf(vx * vx + vy * vy + vz * vz + 1e-12f);
    float fcut = (d < kCutoff) ? 0.5f * (__cosf(kPi * d / kCutoff) + 1.0f) : 0.0f;

    float r[NB];
    #pragma unroll
    for (int i = 0; i < NB; i++) {
        float tt = d - (kCutoff / (NB - 1)) * (float)i;
        r[i] = __expf(-2.0f * tt * tt) * fcut;
    }
    float4 r0 = make_float4(r[0], r[1], r[2], r[3]);
    float4 r1 = make_float4(r[4], r[5], r[6], r[7]);
    float4* dst = (float4*)(rbf_s + (size_t)p * NB);   // coalesced: p = tid
    dst[0] = r0; dst[1] = r1;
    *(float4*)&s_rbf[t][0] = r0;
    *(float4*)&s_rbf[t][4] = r1;
    int spec = species[ni];
    s_ci[t] = ci; s_sp[t] = spec;
    atomicAdd(&ncnt[ci * 4 + spec], 1);
    __syncthreads();

    // phase B: half-wave per pair, j across 32 lanes; H row write is 32
    // contiguous floats -> 1-2 L2 atomic txns per pair.
    int wv = t >> 6, lane = t & 63, hh = lane >> 5, j = lane & 31;
    float b1j = s_b1v[j];              // after barrier (R5 lesson)
    for (int q = 0; q < 32; q++) {
        int idx = wv * 64 + 2 * q + hh;
        float acc = b1j;
        #pragma unroll
        for (int i = 0; i < NB; i++) acc += s_rbf[idx][i] * s_w1[i][j];
        float h = silu(acc);
        int a = s_ci[idx], s = s_sp[idx];
        atomicAdd(&H[(size_t)(a * 4 + s) * RH + j], h);
    }
}

// ---------------------------------------------------------------------------
// K2: atom-parallel G0 from H/ncnt. 2 atoms per 256-thread block.
// ---------------------------------------------------------------------------
__global__ __launch_bounds__(256) void f0b_kernel(
    const float* __restrict__ H, const int* __restrict__ ncnt,
    const float* __restrict__ embed,
    const float* __restrict__ w2, const float* __restrict__ b2,
    const float* __restrict__ mix,
    float* __restrict__ G0)
{
    __shared__ float s_H[2][4 * RH];
    __shared__ float s_n[2][4];
    int t  = threadIdx.x;
    int at = t >> 7;                  // atom slot 0/1
    int k  = t & 127;
    int a  = blockIdx.x * 2 + at;
    s_H[at][k] = H[(size_t)a * 128 + k];      // coalesced
    if (k < 4) s_n[at][k] = (float)ncnt[a * 4 + k];
    __syncthreads();

    float e0 = embed[0 * KD + k], e1 = embed[1 * KD + k];
    float e2 = embed[2 * KD + k], e3 = embed[3 * KD + k];
    float F2 = 0.0f;
    #pragma unroll 4
    for (int j = 0; j < RH; j++) {
        float tj = e0 * s_H[at][0 * RH + j] + e1 * s_H[at][1 * RH + j]
                 + e2 * s_H[at][2 * RH + j] + e3 * s_H[at][3 * RH + j];
        F2 += w2[j * (3 * KD) + k] * tj;
    }
    float F = b2[k] * (s_n[at][0] * e0 + s_n[at][1] * e1
                     + s_n[at][2] * e2 + s_n[at][3] * e3) + F2;
    float F0v = C1 * F;
    G0[(size_t)a * KD + k] = F0v + F0v * F0v * mix[k];
}

// ---------------------------------------------------------------------------
// K3: pair-parallel D accumulation. 1250 blocks x 256, exactly 2 batches
// of 64 pairs per block. Per batch: stage rbf -> h'(erad) in LDS, then
// each wave handles 16 pairs: coalesced G0-row gather (1-deep prefetch),
// 64-FMA dot with w2e columns in regs, fire-and-forget atomicAdd into D.
// Perfect balance; all barriers uniform.
// ---------------------------------------------------------------------------
__global__ __launch_bounds__(256, 2) void d0b_kernel(
    const float* __restrict__ rbf_s,
    const int* __restrict__ ctr, const int* __restrict__ nbr,
    const float* __restrict__ w1e, const float* __restrict__ b1e,
    const float* __restrict__ w2e, const float* __restrict__ b2e,
    const float* __restrict__ G0, float* __restrict__ D)
{
    __shared__ float s_w1[NB][RH];
    __shared__ float s_b1v[RH];
    __shared__ float s_rbf[64][NB];    // 2 KB
    __shared__ float s_h[64][RH];      // 8 KB
    __shared__ int   s_ci[64];
    __shared__ int   s_nbr[64];

    int t = threadIdx.x;
    for (int idx = t; idx < NB * RH; idx += 256)
        s_w1[idx >> 5][idx & 31] = w1e[idx];
    if (t < RH) s_b1v[t] = b1e[t];

    int wv = t >> 6, lane = t & 63;
    int k0 = lane, k1 = lane + 64;
    float w2c0[RH], w2c1[RH];
    #pragma unroll
    for (int j = 0; j < RH; j++) {
        w2c0[j] = w2e[j * (3 * KD) + k0];
        w2c1[j] = w2e[j * (3 * KD) + k1];
    }
    float b2k0 = b2e[k0], b2k1 = b2e[k1];
    __syncthreads();                   // publish s_w1/s_b1v
    float b1j = s_b1v[t & 31];         // after barrier (R5 lesson)

    const int NBATCH = kPairs / 64;    // 2500
    for (int b = blockIdx.x; b < NBATCH; b += gridDim.x) {
        int base = b * 64;
        if (t < 128)
            *(float4*)&s_rbf[t >> 1][(t & 1) * 4] =
                *(const float4*)(rbf_s + (size_t)(base + (t >> 1)) * NB + (t & 1) * 4);
        if (t < 64) { s_ci[t] = ctr[base + t]; s_nbr[t] = nbr[base + t]; }
        __syncthreads();
        // h' for 64 pairs: j = t&31, pair stride 8
        {
            int j = t & 31;
            for (int pp = t >> 5; pp < 64; pp += 8) {
                float acc = b1j;
                #pragma unroll
                for (int i = 0; i < NB; i++) acc += s_rbf[pp][i] * s_w1[i][j];
                s_h[pp][j] = silu(acc);
            }
        }
        __syncthreads();
        // each wave: 16 pairs
        int pbase = wv * 16;
        int nb0 = s_nbr[pbase];
        float gv0n = G0[(size_t)nb0 * KD + k0];
        float gv1n = G0[(size_t)nb0 * KD + k1];
        for (int i = 0; i < 16; i++) {
            float gv0 = gv0n, gv1 = gv1n;
            if (i + 1 < 16) {
                int nbn = s_nbr[pbase + i + 1];
                gv0n = G0[(size_t)nbn * KD + k0];
                gv1n = G0[(size_t)nbn * KD + k1];
            }
            float R0 = b2k0, R1 = b2k1;
            #pragma unroll
            for (int jq = 0; jq < RH / 4; jq++) {
                float4 h4 = *(const float4*)&s_h[pbase + i][4 * jq];
                R0 += h4.x * w2c0[4 * jq + 0] + h4.y * w2c0[4 * jq + 1]
                    + h4.z * w2c0[4 * jq + 2] + h4.w * w2c0[4 * jq + 3];
                R1 += h4.x * w2c1[4 * jq + 0] + h4.y * w2c1[4 * jq + 1]
                    + h4.z * w2c1[4 * jq + 2] + h4.w * w2c1[4 * jq + 3];
            }
            int ci = s_ci[pbase + i];
            atomicAdd(&D[(size_t)ci * KD + k0], R0 * gv0);
            atomicAdd(&D[(size_t)ci * KD + k1], R1 * gv1);
        }
        __syncthreads();               // before next batch overwrites LDS
    }
}

// ---------------------------------------------------------------------------
// K4: head MLP with fused V-finalize (reads G0 + D directly).
// ---------------------------------------------------------------------------
__global__ __launch_bounds__(128) void head_kernel(
    const float* __restrict__ G0, const float* __restrict__ D,
    const float* __restrict__ emix,
    const float* __restrict__ w1, const float* __restrict__ b1,
    const float* __restrict__ w2, const float* __restrict__ b2,
    const float* __restrict__ lw, const float* __restrict__ lb,
    float* __restrict__ out)
{
    __shared__ float s_a[8][KD];
    __shared__ float s_b[8][KD];
    int j = threadIdx.x;
    int abase = blockIdx.x * 8;
    float emj = emix[j];

    #pragma unroll
    for (int a = 0; a < 8; a++) {
        int ga = abase + a;
        float g  = G0[(size_t)ga * KD + j];
        float dd = D[(size_t)ga * KD + j];
        float n0 = g + C2 * dd;
        s_a[a][j] = n0 + n0 * n0 * emj;    // V inline
    }
    __syncthreads();

    float acc[8];
    float bj = b1[j];
    #pragma unroll
    for (int a = 0; a < 8; a++) acc[a] = bj;
    for (int kk = 0; kk < KD; kk += 4) {
        float wa = w1[(kk + 0) * KD + j], wb = w1[(kk + 1) * KD + j];
        float wc = w1[(kk + 2) * KD + j], wd = w1[(kk + 3) * KD + j];
        #pragma unroll
        for (int a = 0; a < 8; a++) {
            float4 v = *(const float4*)&s_a[a][kk];
            acc[a] += v.x * wa + v.y * wb + v.z * wc + v.w * wd;
        }
    }
    #pragma unroll
    for (int a = 0; a < 8; a++) s_b[a][j] = silu(acc[a]);
    __syncthreads();

    float b2j = b2[j];
    #pragma unroll
    for (int a = 0; a < 8; a++) acc[a] = b2j;
    for (int kk = 0; kk < KD; kk += 4) {
        float wa = w2[(kk + 0) * KD + j], wb = w2[(kk + 1) * KD + j];
        float wc = w2[(kk + 2) * KD + j], wd = w2[(kk + 3) * KD + j];
        #pragma unroll
        for (int a = 0; a < 8; a++) {
            float4 v = *(const float4*)&s_b[a][kk];
            acc[a] += v.x * wa + v.y * wb + v.z * wc + v.w * wd;
        }
    }
    float lwj = lw[j];
    __syncthreads();
    #pragma unroll
    for (int a = 0; a < 8; a++) s_a[a][j] = silu(acc[a]) * lwj;
    __syncthreads();
    for (int s = 64; s > 0; s >>= 1) {
        if (j < s) {
            #pragma unroll
            for (int a = 0; a < 8; a++) s_a[a][j] += s_a[a][j + s];
        }
        __syncthreads();
    }
    if (j < 8) {
        int ga = abase + j;
        if (ga < kAtoms) out[ga] = s_a[j][0] + lb[0];
    }
}

// ---------------------------------------------------------------------------
extern "C" void kernel_launch(void* const* d_in, const int* in_sizes, int n_in,
                              void* d_out, int out_size, void* d_ws, size_t ws_size,
                              hipStream_t stream) {
    const float* positions = (const float*)d_in[0];
    const float* cells     = (const float*)d_in[1];
    const int*   species   = (const int*)d_in[2];
    const int*   shifts    = (const int*)d_in[3];
    const int*   ctr       = (const int*)d_in[4];
    const int*   nbr       = (const int*)d_in[5];
    const int*   spair     = (const int*)d_in[6];
    const float* embed     = (const float*)d_in[7];
    const float* rad_w1    = (const float*)d_in[8];
    const float* rad_b1    = (const float*)d_in[9];
    const float* rad_w2    = (const float*)d_in[10];
    const float* rad_b2    = (const float*)d_in[11];
    const float* erad_w1   = (const float*)d_in[12];
    const float* erad_b1   = (const float*)d_in[13];
    const float* erad_w2   = (const float*)d_in[14];
    const float* erad_b2   = (const float*)d_in[15];
    const float* mix_a     = (const float*)d_in[16];
    const float* emix_a    = (const float*)d_in[17];
    const float* head_w1   = (const float*)d_in[18];
    const float* head_b1   = (const float*)d_in[19];
    const float* head_w2   = (const float*)d_in[20];
    const float* head_b2   = (const float*)d_in[21];
    const float* last_w    = (const float*)d_in[22];
    const float* last_b    = (const float*)d_in[23];
    // U2 (d_in[24]) unused: l>=1 channels are dead code for the output.

    float* H     = (float*)d_ws;                          // 5000*128
    int*   ncnt  = (int*)(H + (size_t)kAtoms * KD);       // 5000*4
    float* D     = (float*)(ncnt + (size_t)kAtoms * 4);   // 5000*128
    float* G0    = D + (size_t)kAtoms * KD;               // 5000*128
    float* rbf_s = G0 + (size_t)kAtoms * KD;              // 160000*8

    // zero H + ncnt + D in one contiguous memset
    size_t zero_bytes = (size_t)kAtoms * KD * 4   // H
                      + (size_t)kAtoms * 4 * 4    // ncnt
                      + (size_t)kAtoms * KD * 4;  // D
    hipMemsetAsync(d_ws, 0, zero_bytes, stream);

    build2_kernel<<<kPairs / 256, 256, 0, stream>>>(
        positions, cells, species, shifts, ctr, nbr, spair,
        rad_w1, rad_b1, rbf_s, H, ncnt);

    f0b_kernel<<<kAtoms / 2, 256, 0, stream>>>(
        H, ncnt, embed, rad_w2, rad_b2, mix_a, G0);

    d0b_kernel<<<1250, 256, 0, stream>>>(
        rbf_s, ctr, nbr, erad_w1, erad_b1, erad_w2, erad_b2, G0, D);

    head_kernel<<<kAtoms / 8, 128, 0, stream>>>(
        G0, D, emix_a, head_w1, head_b1, head_w2, head_b2, last_w, last_b,
        (float*)d_out);
}